// Round 5
// baseline (577.108 us; speedup 1.0000x reference)
//
#include <hip/hip_runtime.h>
#include <stdint.h>

// ---------------------------------------------------------------------------
// GPT2 attention forward. INPUTS/OUTPUT ARE FP32 (per reference dtypes) —
// rounds 1-4 misread them as bf16, which decodes fp32 mantissa halves as
// random bf16 incl. NaN encodings. Internally bf16 MFMA (2% rel tolerance).
// Pipeline: convert x -> bf16; convert+transpose W -> bf16; QKV gemm
// (writes Q,K per-head + V transposed, bf16); MFMA flash attention
// (S^T/O^T trick); proj gemm -> fp32 out.
// ---------------------------------------------------------------------------

typedef __bf16 bf16x8 __attribute__((ext_vector_type(8)));
typedef float f32x4 __attribute__((ext_vector_type(4)));

__device__ __forceinline__ f32x4 mfma16(bf16x8 a, bf16x8 b, f32x4 c) {
  return __builtin_amdgcn_mfma_f32_16x16x32_bf16(a, b, c, 0, 0, 0);
}

__device__ __forceinline__ float bf2f(uint16_t h) {
  unsigned int u = ((unsigned int)h) << 16;
  return __builtin_bit_cast(float, u);
}
__device__ __forceinline__ uint16_t f2bf(float f) {
  unsigned int u = __builtin_bit_cast(unsigned int, f);
  u += 0x7fffu + ((u >> 16) & 1u);
  return (uint16_t)(u >> 16);
}

// ---------------------------------------------------------------------------
// fp32 -> bf16 elementwise, 8 elements/thread. grid covers n/8 exactly.
// ---------------------------------------------------------------------------
__global__ __launch_bounds__(256) void f2b_k(const float* __restrict__ in,
                                             uint16_t* __restrict__ out, int n) {
  const int base = (blockIdx.x * 256 + threadIdx.x) * 8;
  if (base >= n) return;
  float4 a = *(const float4*)(in + base);
  float4 b = *(const float4*)(in + base + 4);
  uint16_t t[8];
  t[0] = f2bf(a.x); t[1] = f2bf(a.y); t[2] = f2bf(a.z); t[3] = f2bf(a.w);
  t[4] = f2bf(b.x); t[5] = f2bf(b.y); t[6] = f2bf(b.z); t[7] = f2bf(b.w);
  *(int4*)(out + base) = *(const int4*)t;
}

// ---------------------------------------------------------------------------
// fused convert+transpose: out_bf16[c][r] = in_f32[r][c].
// grid (C/64, R/64), 256 threads.
// ---------------------------------------------------------------------------
__global__ __launch_bounds__(256) void transpose_f2b(const float* __restrict__ in,
                                                     uint16_t* __restrict__ out,
                                                     int R, int C) {
  __shared__ float t[64][65];  // +1 pad: column reads conflict-light
  const int tx = threadIdx.x & 15;   // 16 segments of 4 cols
  const int ty = threadIdx.x >> 4;   // 16 row-groups
  const int r0 = blockIdx.y * 64, c0 = blockIdx.x * 64;
#pragma unroll
  for (int rr = ty; rr < 64; rr += 16) {
    float4 v = *(const float4*)(in + (size_t)(r0 + rr) * C + c0 + tx * 4);
    t[rr][tx * 4 + 0] = v.x; t[rr][tx * 4 + 1] = v.y;
    t[rr][tx * 4 + 2] = v.z; t[rr][tx * 4 + 3] = v.w;
  }
  __syncthreads();
#pragma unroll
  for (int cc = ty; cc < 64; cc += 16) {
    uint16_t tmp[4];
#pragma unroll
    for (int j = 0; j < 4; j++) tmp[j] = f2bf(t[tx * 4 + j][cc]);
    *(uint2*)(out + (size_t)(c0 + cc) * R + r0 + tx * 4) = *(const uint2*)tmp;
  }
}

// ---------------------------------------------------------------------------
// bt-form GEMM: C[m][n] = A[m][:] . Bt[n][:] + bias[n]. A,Bt bf16; bias fp32.
// K=1024, tile 128x128, m97 pattern (register-round-trip staging).
// EPI==0: QKV scatter (outQ/outK = [h][s][d] bf16, outV = V^T [h][d][s] bf16)
// EPI==1: plain fp32 epilogue (outF[m*1024+n])
// ---------------------------------------------------------------------------
template <int EPI>
__global__ __launch_bounds__(256) void gemm_bt(const uint16_t* __restrict__ A,
                                               const uint16_t* __restrict__ Bt,
                                               const float* __restrict__ bias,
                                               uint16_t* __restrict__ outQ,
                                               uint16_t* __restrict__ outK,
                                               uint16_t* __restrict__ outV,
                                               float* __restrict__ outF) {
  __shared__ __align__(16) uint16_t lA[128 * 32];
  __shared__ __align__(16) uint16_t lB[128 * 32];
  const int tid = threadIdx.x;
  const int w = tid >> 6, lane = tid & 63;
  const int quad = lane >> 4, c16 = lane & 15;
  const int m0 = blockIdx.y * 128, n0 = blockIdx.x * 128;

  f32x4 acc[4][4];
#pragma unroll
  for (int i = 0; i < 4; i++)
#pragma unroll
    for (int j = 0; j < 4; j++) acc[i][j] = f32x4{0.f, 0.f, 0.f, 0.f};

  // tile 128 rows x 32 cols bf16 = 8KB. LDS row = 64B = 4 chunks of 16B;
  // chunk swizzle c' = c ^ ((row>>1)&3).
  for (int k0 = 0; k0 < 1024; k0 += 32) {
    __syncthreads();
    int4 va[2], vb[2];
#pragma unroll
    for (int ii = 0; ii < 2; ii++) {
      const int p16 = (w * 2 + ii) * 64 + lane;  // 0..511
      const int row = p16 >> 2, cp = p16 & 3;
      const int c = cp ^ ((row >> 1) & 3);
      va[ii] = *(const int4*)(A + (size_t)(m0 + row) * 1024 + k0 + c * 8);
      vb[ii] = *(const int4*)(Bt + (size_t)(n0 + row) * 1024 + k0 + c * 8);
    }
#pragma unroll
    for (int ii = 0; ii < 2; ii++) {
      const int p16 = (w * 2 + ii) * 64 + lane;
      *(int4*)((char*)lA + (size_t)p16 * 16) = va[ii];
      *(int4*)((char*)lB + (size_t)p16 * 16) = vb[ii];
    }
    __syncthreads();
    bf16x8 af[4], bfr[4];
#pragma unroll
    for (int t = 0; t < 4; t++) {
      const int mr = (w >> 1) * 64 + t * 16 + c16;
      af[t] = *(const bf16x8*)((const char*)lA + mr * 64 + ((quad ^ ((mr >> 1) & 3)) * 16));
      const int nr = (w & 1) * 64 + t * 16 + c16;
      bfr[t] = *(const bf16x8*)((const char*)lB + nr * 64 + ((quad ^ ((nr >> 1) & 3)) * 16));
    }
#pragma unroll
    for (int i = 0; i < 4; i++)
#pragma unroll
      for (int j = 0; j < 4; j++) acc[i][j] = mfma16(af[i], bfr[j], acc[i][j]);
  }

  // epilogue. C/D layout per 16x16 tile: col = lane&15, row = quad*4+r.
  const int mbase = m0 + (w >> 1) * 64;
  const int nbase = n0 + (w & 1) * 64;
  float bv[4];
#pragma unroll
  for (int j = 0; j < 4; j++) bv[j] = bias[nbase + j * 16 + c16];
#pragma unroll
  for (int i = 0; i < 4; i++) {
#pragma unroll
    for (int j = 0; j < 4; j++) {
      const int n = nbase + j * 16 + c16;
#pragma unroll
      for (int r = 0; r < 4; r++) {
        const int m = mbase + i * 16 + quad * 4 + r;
        const float fv = acc[i][j][r] + bv[j];
        if (EPI == 0) {
          const uint16_t b = f2bf(fv);
          const int region = n >> 10;  // 0=Q 1=K 2=V (uniform per block)
          const int cr = n & 1023;
          const int h = cr >> 6, d = cr & 63;
          if (region == 0)      outQ[((size_t)(h << 12) + m) * 64 + d] = b;
          else if (region == 1) outK[((size_t)(h << 12) + m) * 64 + d] = b;
          else                  outV[((size_t)(h * 64 + d) << 12) + m] = b;  // V^T
        } else {
          outF[(size_t)m * 1024 + n] = fv;
        }
      }
    }
  }
}

// ---------------------------------------------------------------------------
// MFMA flash attention, one (head, 128-q-row tile) per block, 4 waves x 32 q.
// Computes S^T = K.Q^T and O^T = Vt.P^T (softmax row q = lane&15).
// ---------------------------------------------------------------------------
__global__ __launch_bounds__(256) void attn_kernel(const uint16_t* __restrict__ Qb,
                                                   const uint16_t* __restrict__ Kb,
                                                   const uint16_t* __restrict__ Vtb,
                                                   uint16_t* __restrict__ Ob) {
  __shared__ __align__(16) uint16_t lK[128 * 64];      // [key][d], 8 chunks/row
  __shared__ __align__(16) uint16_t lV[64 * 128];      // [d][key], 16 chunks/row
  __shared__ __align__(16) uint16_t lP[4 * 32 * 128];  // per-wave [q][key]
  const int tid = threadIdx.x;
  const int w = tid >> 6, lane = tid & 63;
  const int quad = lane >> 4, c16 = lane & 15;
  const int qb = 31 - (int)blockIdx.x;  // heavy tiles first
  const int h = blockIdx.y;
  const int q0w = qb * 128 + w * 32;

  // Q fragments (B-operand): lane holds q(n)=c16, k(d) = kc*32 + quad*8 + j
  bf16x8 qf[2][2];
#pragma unroll
  for (int nt = 0; nt < 2; nt++)
#pragma unroll
    for (int kc = 0; kc < 2; kc++) {
      int4 v = *(const int4*)(Qb + ((size_t)(h << 12) + q0w + nt * 16 + c16) * 64 + kc * 32 + quad * 8);
      qf[nt][kc] = __builtin_bit_cast(bf16x8, v);
    }

  float ms[2] = {-3.0e38f, -3.0e38f};
  float ls[2] = {0.f, 0.f};
  f32x4 o[4][2];
#pragma unroll
  for (int i = 0; i < 4; i++) { o[i][0] = f32x4{0.f,0.f,0.f,0.f}; o[i][1] = f32x4{0.f,0.f,0.f,0.f}; }

  for (int j = 0; j <= qb; j++) {
    __syncthreads();  // all waves done reading lK/lV of prev iter
    // stage K tile (16KB) and Vt tile (16KB) via register round-trip
    int4 vk[4], vv[4];
#pragma unroll
    for (int ii = 0; ii < 4; ii++) {
      const int p16 = (w * 4 + ii) * 64 + lane;  // 0..1023
      const int rowK = p16 >> 3, cpK = p16 & 7, cK = cpK ^ (rowK & 7);
      vk[ii] = *(const int4*)(Kb + ((size_t)(h << 12) + j * 128 + rowK) * 64 + cK * 8);
      const int dV = p16 >> 4, cpV = p16 & 15, cV = cpV ^ (dV & 15);
      vv[ii] = *(const int4*)(Vtb + ((size_t)(h * 64 + dV) << 12) + j * 128 + cV * 8);
    }
#pragma unroll
    for (int ii = 0; ii < 4; ii++) {
      const int p16 = (w * 4 + ii) * 64 + lane;
      *(int4*)((char*)lK + (size_t)p16 * 16) = vk[ii];
      *(int4*)((char*)lV + (size_t)p16 * 16) = vv[ii];
    }
    __syncthreads();

    // ---- S^T = K . Q^T : D[key][q], 8 key-tiles x 2 q-tiles
    f32x4 st[8][2];
#pragma unroll
    for (int mt = 0; mt < 8; mt++) { st[mt][0] = f32x4{0.f,0.f,0.f,0.f}; st[mt][1] = f32x4{0.f,0.f,0.f,0.f}; }
#pragma unroll
    for (int kc = 0; kc < 2; kc++) {
#pragma unroll
      for (int mt = 0; mt < 8; mt++) {
        const int row = mt * 16 + c16;
        bf16x8 a = *(const bf16x8*)((const char*)lK + row * 128 + (((kc * 4 + quad) ^ (row & 7)) * 16));
        st[mt][0] = mfma16(a, qf[0][kc], st[mt][0]);
        st[mt][1] = mfma16(a, qf[1][kc], st[mt][1]);
      }
    }

    const bool diag = (j == qb);
    // ---- online softmax (per q = c16, state replicated across quads)
#pragma unroll
    for (int nt = 0; nt < 2; nt++) {
      const int qg = q0w + nt * 16 + c16;
#pragma unroll
      for (int mt = 0; mt < 8; mt++)
#pragma unroll
        for (int r = 0; r < 4; r++) {
          float v = st[mt][nt][r] * 0.125f;
          if (diag) {
            const int key = j * 128 + mt * 16 + quad * 4 + r;
            if (key > qg) v = -1.0e9f;
          }
          st[mt][nt][r] = v;
        }
      float mx = -3.0e38f;
#pragma unroll
      for (int mt = 0; mt < 8; mt++)
#pragma unroll
        for (int r = 0; r < 4; r++) mx = fmaxf(mx, st[mt][nt][r]);
      mx = fmaxf(mx, __shfl_xor(mx, 16));
      mx = fmaxf(mx, __shfl_xor(mx, 32));
      const float mnew = fmaxf(ms[nt], mx);
      const float alpha = __expf(ms[nt] - mnew);
      float sum = 0.f;
      const int prow = nt * 16 + c16;
      const size_t pbase = (size_t)w * 8192 + (size_t)prow * 256;
#pragma unroll
      for (int mt = 0; mt < 8; mt++) {
        float p0 = __expf(st[mt][nt][0] - mnew);
        float p1 = __expf(st[mt][nt][1] - mnew);
        float p2 = __expf(st[mt][nt][2] - mnew);
        float p3 = __expf(st[mt][nt][3] - mnew);
        sum += p0 + p1 + p2 + p3;
        const unsigned int lo = (unsigned int)f2bf(p0) | ((unsigned int)f2bf(p1) << 16);
        const unsigned int hi = (unsigned int)f2bf(p2) | ((unsigned int)f2bf(p3) << 16);
        const int chunk = mt * 2 + (quad >> 1);
        uint2* dst = (uint2*)((char*)lP + pbase + ((chunk ^ (prow & 15)) << 4) + (quad & 1) * 8);
        *dst = make_uint2(lo, hi);
      }
      sum += __shfl_xor(sum, 16);
      sum += __shfl_xor(sum, 32);
      ls[nt] = alpha * ls[nt] + sum;
      ms[nt] = mnew;
#pragma unroll
      for (int mt = 0; mt < 4; mt++) o[mt][nt] *= alpha;
    }
    // lP is per-wave (same wave writes then reads, in order): no barrier.

    // ---- O^T += Vt . P^T : D[d][q], 4 d-tiles x 2 q-tiles, K over 128 keys
#pragma unroll
    for (int kc = 0; kc < 4; kc++) {
      bf16x8 pb[2];
#pragma unroll
      for (int nt = 0; nt < 2; nt++) {
        const int prow = nt * 16 + c16;
        const int chunk = kc * 4 + quad;
        pb[nt] = *(const bf16x8*)((const char*)lP + (size_t)w * 8192 + (size_t)prow * 256 +
                                  ((chunk ^ (prow & 15)) << 4));
      }
#pragma unroll
      for (int mt = 0; mt < 4; mt++) {
        const int d = mt * 16 + c16;
        bf16x8 a = *(const bf16x8*)((const char*)lV + d * 256 + (((kc * 4 + quad) ^ (d & 15)) * 16));
        o[mt][0] = mfma16(a, pb[0], o[mt][0]);
        o[mt][1] = mfma16(a, pb[1], o[mt][1]);
      }
    }
  }

  // ---- epilogue: Ob[s][h*64+d] = O^T[d][s] / l   (bf16)
#pragma unroll
  for (int nt = 0; nt < 2; nt++) {
    const float inv = 1.f / ls[nt];
    const int qg = q0w + nt * 16 + c16;
#pragma unroll
    for (int mt = 0; mt < 4; mt++)
#pragma unroll
      for (int r = 0; r < 4; r++) {
        const int d = mt * 16 + quad * 4 + r;
        Ob[(size_t)qg * 1024 + h * 64 + d] = f2bf(o[mt][nt][r] * inv);
      }
  }
}

// ---------------------------------------------------------------------------
extern "C" void kernel_launch(void* const* d_in, const int* in_sizes, int n_in,
                              void* d_out, int out_size, void* d_ws, size_t ws_size,
                              hipStream_t stream) {
  const float* x      = (const float*)d_in[0];   // fp32 [1][4096][1024]
  // d_in[1] = attention_mask (fp32): analytically causal, never read
  const float* W_attn = (const float*)d_in[2];   // fp32 [1024][3072]
  const float* b_attn = (const float*)d_in[3];   // fp32 [3072]
  const float* W_proj = (const float*)d_in[4];   // fp32 [1024][1024]
  const float* b_proj = (const float*)d_in[5];   // fp32 [1024]
  float* out = (float*)d_out;                    // fp32 [4096][1024]

  // Workspace (40 MB). Ob aliases xb: xb dead after QKV gemm (stream order).
  char* ws = (char*)d_ws;
  uint16_t* xb  = (uint16_t*)(ws);                    // [0,8MB): x bf16 [4096][1024]
  uint16_t* Ob  = (uint16_t*)(ws);                    // [0,8MB): attn out bf16
  uint16_t* wtA = (uint16_t*)(ws + 8388608);          // [8,14MB): W_attn^T bf16 [3072][1024]
  uint16_t* wtP = (uint16_t*)(ws + 14680064);         // [14,16MB): W_proj^T bf16 [1024][1024]
  uint16_t* Qb  = (uint16_t*)(ws + 16777216);         // [16,24MB): Q bf16 [16][4096][64]
  uint16_t* Kb  = (uint16_t*)(ws + 25165824);         // [24,32MB): K bf16 [16][4096][64]
  uint16_t* Vtb = (uint16_t*)(ws + 33554432);         // [32,40MB): V^T bf16 [16][64][4096]

  f2b_k<<<2048, 256, 0, stream>>>(x, xb, 4096 * 1024);
  transpose_f2b<<<dim3(48, 16), 256, 0, stream>>>(W_attn, wtA, 1024, 3072);
  transpose_f2b<<<dim3(16, 16), 256, 0, stream>>>(W_proj, wtP, 1024, 1024);
  gemm_bt<0><<<dim3(24, 32), 256, 0, stream>>>(xb, wtA, b_attn, Qb, Kb, Vtb, nullptr);
  attn_kernel<<<dim3(32, 16), 256, 0, stream>>>(Qb, Kb, Vtb, Ob);
  gemm_bt<1><<<dim3(8, 32), 256, 0, stream>>>(Ob, wtP, b_proj, nullptr, nullptr, nullptr, out);
}

// Round 6
// 468.304 us; speedup vs baseline: 1.2323x; 1.2323x over previous
//
#include <hip/hip_runtime.h>
#include <stdint.h>

// ---------------------------------------------------------------------------
// GPT2 attention forward, fp32 in/out, bf16 MFMA internally.
// Round 6: attention restructured — K/V consumed as A-fragments DIRECTLY from
// global (no LDS staging, no barriers in the K-loop; lP is per-wave). Q is
// prescaled by 0.125 in the QKV epilogue. Ob is fp32 so both GEMMs use fp32 A
// (convert during staging), deleting the standalone convert kernel.
// ---------------------------------------------------------------------------

typedef __bf16 bf16x8 __attribute__((ext_vector_type(8)));
typedef float f32x4 __attribute__((ext_vector_type(4)));

__device__ __forceinline__ f32x4 mfma16(bf16x8 a, bf16x8 b, f32x4 c) {
  return __builtin_amdgcn_mfma_f32_16x16x32_bf16(a, b, c, 0, 0, 0);
}

__device__ __forceinline__ uint16_t f2bf(float f) {
  unsigned int u = __builtin_bit_cast(unsigned int, f);
  u += 0x7fffu + ((u >> 16) & 1u);
  return (uint16_t)(u >> 16);
}

// ---------------------------------------------------------------------------
// fused convert+transpose: out_bf16[c][r] = in_f32[r][c]. grid (C/64, R/64).
// ---------------------------------------------------------------------------
__global__ __launch_bounds__(256) void transpose_f2b(const float* __restrict__ in,
                                                     uint16_t* __restrict__ out,
                                                     int R, int C) {
  __shared__ float t[64][65];
  const int tx = threadIdx.x & 15;
  const int ty = threadIdx.x >> 4;
  const int r0 = blockIdx.y * 64, c0 = blockIdx.x * 64;
#pragma unroll
  for (int rr = ty; rr < 64; rr += 16) {
    float4 v = *(const float4*)(in + (size_t)(r0 + rr) * C + c0 + tx * 4);
    t[rr][tx * 4 + 0] = v.x; t[rr][tx * 4 + 1] = v.y;
    t[rr][tx * 4 + 2] = v.z; t[rr][tx * 4 + 3] = v.w;
  }
  __syncthreads();
#pragma unroll
  for (int cc = ty; cc < 64; cc += 16) {
    uint16_t tmp[4];
#pragma unroll
    for (int j = 0; j < 4; j++) tmp[j] = f2bf(t[tx * 4 + j][cc]);
    *(uint2*)(out + (size_t)(c0 + cc) * R + r0 + tx * 4) = *(const uint2*)tmp;
  }
}

// ---------------------------------------------------------------------------
// bt-form GEMM: C[m][n] = A[m][:].Bt[n][:] + bias[n]. A fp32 (converted to
// bf16 during staging), Bt bf16, bias fp32. K=1024, tile 128x128.
// EPI==0: QKV scatter (Q prescaled by 0.125; outV = V^T [h][d][s])
// EPI==1: plain fp32 epilogue (outF[m*1024+n])
// ---------------------------------------------------------------------------
template <int EPI>
__global__ __launch_bounds__(256) void gemm_bt(const float* __restrict__ A,
                                               const uint16_t* __restrict__ Bt,
                                               const float* __restrict__ bias,
                                               uint16_t* __restrict__ outQ,
                                               uint16_t* __restrict__ outK,
                                               uint16_t* __restrict__ outV,
                                               float* __restrict__ outF) {
  __shared__ __align__(16) uint16_t lA[128 * 32];
  __shared__ __align__(16) uint16_t lB[128 * 32];
  const int tid = threadIdx.x;
  const int w = tid >> 6, lane = tid & 63;
  const int quad = lane >> 4, c16 = lane & 15;
  const int m0 = blockIdx.y * 128, n0 = blockIdx.x * 128;

  f32x4 acc[4][4];
#pragma unroll
  for (int i = 0; i < 4; i++)
#pragma unroll
    for (int j = 0; j < 4; j++) acc[i][j] = f32x4{0.f, 0.f, 0.f, 0.f};

  // LDS row = 64B = 4 chunks of 16B; chunk swizzle c' = c ^ ((row>>1)&3).
  for (int k0 = 0; k0 < 1024; k0 += 32) {
    __syncthreads();
    float4 fa[2][2]; int4 vb[2];
#pragma unroll
    for (int ii = 0; ii < 2; ii++) {
      const int p16 = (w * 2 + ii) * 64 + lane;  // 0..511
      const int row = p16 >> 2, cp = p16 & 3;
      const int c = cp ^ ((row >> 1) & 3);
      fa[ii][0] = *(const float4*)(A + (size_t)(m0 + row) * 1024 + k0 + c * 8);
      fa[ii][1] = *(const float4*)(A + (size_t)(m0 + row) * 1024 + k0 + c * 8 + 4);
      vb[ii] = *(const int4*)(Bt + (size_t)(n0 + row) * 1024 + k0 + c * 8);
    }
#pragma unroll
    for (int ii = 0; ii < 2; ii++) {
      const int p16 = (w * 2 + ii) * 64 + lane;
      uint16_t tmp[8];
      tmp[0] = f2bf(fa[ii][0].x); tmp[1] = f2bf(fa[ii][0].y);
      tmp[2] = f2bf(fa[ii][0].z); tmp[3] = f2bf(fa[ii][0].w);
      tmp[4] = f2bf(fa[ii][1].x); tmp[5] = f2bf(fa[ii][1].y);
      tmp[6] = f2bf(fa[ii][1].z); tmp[7] = f2bf(fa[ii][1].w);
      *(int4*)((char*)lA + (size_t)p16 * 16) = *(const int4*)tmp;
      *(int4*)((char*)lB + (size_t)p16 * 16) = vb[ii];
    }
    __syncthreads();
    bf16x8 af[4], bfr[4];
#pragma unroll
    for (int t = 0; t < 4; t++) {
      const int mr = (w >> 1) * 64 + t * 16 + c16;
      af[t] = *(const bf16x8*)((const char*)lA + mr * 64 + ((quad ^ ((mr >> 1) & 3)) * 16));
      const int nr = (w & 1) * 64 + t * 16 + c16;
      bfr[t] = *(const bf16x8*)((const char*)lB + nr * 64 + ((quad ^ ((nr >> 1) & 3)) * 16));
    }
#pragma unroll
    for (int i = 0; i < 4; i++)
#pragma unroll
      for (int j = 0; j < 4; j++) acc[i][j] = mfma16(af[i], bfr[j], acc[i][j]);
  }

  // epilogue. C/D layout per 16x16 tile: col = lane&15, row = quad*4+r.
  const int mbase = m0 + (w >> 1) * 64;
  const int nbase = n0 + (w & 1) * 64;
  float bv[4];
#pragma unroll
  for (int j = 0; j < 4; j++) bv[j] = bias[nbase + j * 16 + c16];
#pragma unroll
  for (int i = 0; i < 4; i++) {
#pragma unroll
    for (int j = 0; j < 4; j++) {
      const int n = nbase + j * 16 + c16;
#pragma unroll
      for (int r = 0; r < 4; r++) {
        const int m = mbase + i * 16 + quad * 4 + r;
        float fv = acc[i][j][r] + bv[j];
        if (EPI == 0) {
          const int region = n >> 10;  // 0=Q 1=K 2=V (uniform per block)
          const int cr = n & 1023;
          const int h = cr >> 6, d = cr & 63;
          if (region == 0)      outQ[((size_t)(h << 12) + m) * 64 + d] = f2bf(fv * 0.125f);
          else if (region == 1) outK[((size_t)(h << 12) + m) * 64 + d] = f2bf(fv);
          else                  outV[((size_t)(h * 64 + d) << 12) + m] = f2bf(fv);  // V^T
        } else {
          outF[(size_t)m * 1024 + n] = fv;
        }
      }
    }
  }
}

// ---------------------------------------------------------------------------
// Flash attention, one (head, 128-q-row tile) per block, 4 waves x 32 q rows.
// S^T = K.Q^T and O^T = Vt.P^T. K/V fragments loaded DIRECTLY from global
// (A-operand layout is naturally coalesced); lP is per-wave; NO barriers in
// the K-loop. Q prescaled by 0.125 upstream. Ob written fp32.
// ---------------------------------------------------------------------------
__global__ __launch_bounds__(256, 2) void attn_kernel(const uint16_t* __restrict__ Qb,
                                                      const uint16_t* __restrict__ Kb,
                                                      const uint16_t* __restrict__ Vtb,
                                                      float* __restrict__ Ob) {
  __shared__ __align__(16) uint16_t lP[4 * 32 * 128];  // per-wave [q][key], 8KB/wave
  const int tid = threadIdx.x;
  const int w = tid >> 6, lane = tid & 63;
  const int quad = lane >> 4, c16 = lane & 15;
  const int qb = 31 - (int)blockIdx.x;  // heavy tiles first
  const int h = blockIdx.y;
  const int q0w = qb * 128 + w * 32;

  // Q fragments (B-operand): lane holds q(n)=c16, k(d) = kc*32 + quad*8 + j
  bf16x8 qf[2][2];
#pragma unroll
  for (int nt = 0; nt < 2; nt++)
#pragma unroll
    for (int kc = 0; kc < 2; kc++) {
      int4 v = *(const int4*)(Qb + ((size_t)(h << 12) + q0w + nt * 16 + c16) * 64 + kc * 32 + quad * 8);
      qf[nt][kc] = __builtin_bit_cast(bf16x8, v);
    }

  float ms[2] = {-3.0e38f, -3.0e38f};
  float ls[2] = {0.f, 0.f};
  f32x4 o[4][2];
#pragma unroll
  for (int i = 0; i < 4; i++) { o[i][0] = f32x4{0.f,0.f,0.f,0.f}; o[i][1] = f32x4{0.f,0.f,0.f,0.f}; }

  for (int j = 0; j <= qb; j++) {
    // ---- S^T = K . Q^T : D[key][q]. A-frag: lane m=c16(key row), k=quad*8+j.
    const uint16_t* kbase = Kb + ((size_t)(h << 12) + j * 128) * 64;
    f32x4 st[8][2];
#pragma unroll
    for (int mt = 0; mt < 8; mt++) { st[mt][0] = f32x4{0.f,0.f,0.f,0.f}; st[mt][1] = f32x4{0.f,0.f,0.f,0.f}; }
#pragma unroll
    for (int kc = 0; kc < 2; kc++) {
#pragma unroll
      for (int mt = 0; mt < 8; mt++) {
        int4 v = *(const int4*)(kbase + (mt * 16 + c16) * 64 + kc * 32 + quad * 8);
        bf16x8 a = __builtin_bit_cast(bf16x8, v);
        st[mt][0] = mfma16(a, qf[0][kc], st[mt][0]);
        st[mt][1] = mfma16(a, qf[1][kc], st[mt][1]);
      }
    }

    // ---- causal mask: only on the diagonal tile (uniform branch)
    if (j == qb) {
#pragma unroll
      for (int nt = 0; nt < 2; nt++) {
        const int qg = q0w + nt * 16 + c16;
#pragma unroll
        for (int mt = 0; mt < 8; mt++)
#pragma unroll
          for (int r = 0; r < 4; r++) {
            const int key = j * 128 + mt * 16 + quad * 4 + r;
            if (key > qg) st[mt][nt][r] = -1.0e9f;
          }
      }
    }

    // ---- online softmax (per q = c16, state replicated across quads)
#pragma unroll
    for (int nt = 0; nt < 2; nt++) {
      float mx = -3.0e38f;
#pragma unroll
      for (int mt = 0; mt < 8; mt++)
#pragma unroll
        for (int r = 0; r < 4; r++) mx = fmaxf(mx, st[mt][nt][r]);
      mx = fmaxf(mx, __shfl_xor(mx, 16));
      mx = fmaxf(mx, __shfl_xor(mx, 32));
      const float mnew = fmaxf(ms[nt], mx);
      const float alpha = __expf(ms[nt] - mnew);
      float sum = 0.f;
      const int prow = nt * 16 + c16;
      const size_t pbase = (size_t)w * 8192 + (size_t)prow * 256;
#pragma unroll
      for (int mt = 0; mt < 8; mt++) {
        float p0 = __expf(st[mt][nt][0] - mnew);
        float p1 = __expf(st[mt][nt][1] - mnew);
        float p2 = __expf(st[mt][nt][2] - mnew);
        float p3 = __expf(st[mt][nt][3] - mnew);
        sum += p0 + p1 + p2 + p3;
        const unsigned int lo = (unsigned int)f2bf(p0) | ((unsigned int)f2bf(p1) << 16);
        const unsigned int hi = (unsigned int)f2bf(p2) | ((unsigned int)f2bf(p3) << 16);
        const int chunk = mt * 2 + (quad >> 1);
        uint2* dst = (uint2*)((char*)lP + pbase + ((chunk ^ (prow & 15)) << 4) + (quad & 1) * 8);
        *dst = make_uint2(lo, hi);
      }
      sum += __shfl_xor(sum, 16);
      sum += __shfl_xor(sum, 32);
      ls[nt] = alpha * ls[nt] + sum;
      ms[nt] = mnew;
#pragma unroll
      for (int mt = 0; mt < 4; mt++) o[mt][nt] *= alpha;
    }
    // lP is per-wave (same wave writes then reads, in order): no barrier.

    // ---- O^T += Vt . P^T : D[d][q]. V A-frag direct from global:
    //      lane m=c16 (d row), keys = j*128 + (kc*4+quad)*8 .. +7.
#pragma unroll
    for (int kc = 0; kc < 4; kc++) {
      bf16x8 pb[2];
#pragma unroll
      for (int nt = 0; nt < 2; nt++) {
        const int prow = nt * 16 + c16;
        const int chunk = kc * 4 + quad;
        pb[nt] = *(const bf16x8*)((const char*)lP + (size_t)w * 8192 + (size_t)prow * 256 +
                                  ((chunk ^ (prow & 15)) << 4));
      }
#pragma unroll
      for (int mt = 0; mt < 4; mt++) {
        int4 vv = *(const int4*)(Vtb + ((size_t)(h * 64 + mt * 16 + c16) << 12) +
                                 j * 128 + (kc * 4 + quad) * 8);
        bf16x8 a = __builtin_bit_cast(bf16x8, vv);
        o[mt][0] = mfma16(a, pb[0], o[mt][0]);
        o[mt][1] = mfma16(a, pb[1], o[mt][1]);
      }
    }
  }

  // ---- epilogue: Ob[s][h*64+d] = O^T[d][s] / l   (fp32, float4 stores)
#pragma unroll
  for (int nt = 0; nt < 2; nt++) {
    const float inv = 1.f / ls[nt];
    const int qg = q0w + nt * 16 + c16;
#pragma unroll
    for (int mt = 0; mt < 4; mt++) {
      f32x4 v = o[mt][nt] * inv;
      *(f32x4*)(Ob + (size_t)qg * 1024 + h * 64 + mt * 16 + quad * 4) = v;
    }
  }
}

// ---------------------------------------------------------------------------
extern "C" void kernel_launch(void* const* d_in, const int* in_sizes, int n_in,
                              void* d_out, int out_size, void* d_ws, size_t ws_size,
                              hipStream_t stream) {
  const float* x      = (const float*)d_in[0];   // fp32 [1][4096][1024]
  // d_in[1] = attention_mask (fp32): analytically causal, never read
  const float* W_attn = (const float*)d_in[2];   // fp32 [1024][3072]
  const float* b_attn = (const float*)d_in[3];   // fp32 [3072]
  const float* W_proj = (const float*)d_in[4];   // fp32 [1024][1024]
  const float* b_proj = (const float*)d_in[5];   // fp32 [1024]
  float* out = (float*)d_out;                    // fp32 [4096][1024]

  // Workspace (48 MB).
  char* ws = (char*)d_ws;
  float*    Ob  = (float*)(ws);                       // [0,16MB): attn out fp32 [4096][1024]
  uint16_t* wtA = (uint16_t*)(ws + 16777216);         // [16,22MB): W_attn^T bf16 [3072][1024]
  uint16_t* wtP = (uint16_t*)(ws + 23068672);         // [22,24MB): W_proj^T bf16 [1024][1024]
  uint16_t* Qb  = (uint16_t*)(ws + 25165824);         // Q bf16 [16][4096][64] (prescaled 1/8)
  uint16_t* Kb  = (uint16_t*)(ws + 33554432);         // K bf16 [16][4096][64]
  uint16_t* Vtb = (uint16_t*)(ws + 41943040);         // V^T bf16 [16][64][4096]

  transpose_f2b<<<dim3(48, 16), 256, 0, stream>>>(W_attn, wtA, 1024, 3072);
  transpose_f2b<<<dim3(16, 16), 256, 0, stream>>>(W_proj, wtP, 1024, 1024);
  gemm_bt<0><<<dim3(24, 32), 256, 0, stream>>>(x, wtA, b_attn, Qb, Kb, Vtb, nullptr);
  attn_kernel<<<dim3(32, 16), 256, 0, stream>>>(Qb, Kb, Vtb, Ob);
  gemm_bt<1><<<dim3(8, 32), 256, 0, stream>>>(Ob, wtP, b_proj, nullptr, nullptr, nullptr, out);
}

// Round 7
// 361.415 us; speedup vs baseline: 1.5968x; 1.2958x over previous
//
#include <hip/hip_runtime.h>
#include <stdint.h>

// ---------------------------------------------------------------------------
// GPT2 attention forward, fp32 in/out, bf16 MFMA internally.
// Round 7: attention latency fixes — (1) batched/hoisted K and V fragment
// loads (V latency hidden under softmax), (2) 1-wave blocks, grid 2048 =
// exactly resident at 2 waves/SIMD, (3) head-major 1-D grid so XCD = bid%8
// pins each head's KV to one XCD's L2.
// ---------------------------------------------------------------------------

typedef __bf16 bf16x8 __attribute__((ext_vector_type(8)));
typedef float f32x4 __attribute__((ext_vector_type(4)));

__device__ __forceinline__ f32x4 mfma16(bf16x8 a, bf16x8 b, f32x4 c) {
  return __builtin_amdgcn_mfma_f32_16x16x32_bf16(a, b, c, 0, 0, 0);
}

__device__ __forceinline__ uint16_t f2bf(float f) {
  unsigned int u = __builtin_bit_cast(unsigned int, f);
  u += 0x7fffu + ((u >> 16) & 1u);
  return (uint16_t)(u >> 16);
}

// ---------------------------------------------------------------------------
// fused convert+transpose: out_bf16[c][r] = in_f32[r][c]. grid (C/64, R/64).
// ---------------------------------------------------------------------------
__global__ __launch_bounds__(256) void transpose_f2b(const float* __restrict__ in,
                                                     uint16_t* __restrict__ out,
                                                     int R, int C) {
  __shared__ float t[64][65];
  const int tx = threadIdx.x & 15;
  const int ty = threadIdx.x >> 4;
  const int r0 = blockIdx.y * 64, c0 = blockIdx.x * 64;
#pragma unroll
  for (int rr = ty; rr < 64; rr += 16) {
    float4 v = *(const float4*)(in + (size_t)(r0 + rr) * C + c0 + tx * 4);
    t[rr][tx * 4 + 0] = v.x; t[rr][tx * 4 + 1] = v.y;
    t[rr][tx * 4 + 2] = v.z; t[rr][tx * 4 + 3] = v.w;
  }
  __syncthreads();
#pragma unroll
  for (int cc = ty; cc < 64; cc += 16) {
    uint16_t tmp[4];
#pragma unroll
    for (int j = 0; j < 4; j++) tmp[j] = f2bf(t[tx * 4 + j][cc]);
    *(uint2*)(out + (size_t)(c0 + cc) * R + r0 + tx * 4) = *(const uint2*)tmp;
  }
}

// ---------------------------------------------------------------------------
// bt-form GEMM: C[m][n] = A[m][:].Bt[n][:] + bias[n]. A fp32 (converted to
// bf16 during staging), Bt bf16, bias fp32. K=1024, tile 128x128.
// EPI==0: QKV scatter (Q prescaled by 0.125; outV = V^T [h][d][s])
// EPI==1: plain fp32 epilogue (outF[m*1024+n])
// ---------------------------------------------------------------------------
template <int EPI>
__global__ __launch_bounds__(256) void gemm_bt(const float* __restrict__ A,
                                               const uint16_t* __restrict__ Bt,
                                               const float* __restrict__ bias,
                                               uint16_t* __restrict__ outQ,
                                               uint16_t* __restrict__ outK,
                                               uint16_t* __restrict__ outV,
                                               float* __restrict__ outF) {
  __shared__ __align__(16) uint16_t lA[128 * 32];
  __shared__ __align__(16) uint16_t lB[128 * 32];
  const int tid = threadIdx.x;
  const int w = tid >> 6, lane = tid & 63;
  const int quad = lane >> 4, c16 = lane & 15;
  const int m0 = blockIdx.y * 128, n0 = blockIdx.x * 128;

  f32x4 acc[4][4];
#pragma unroll
  for (int i = 0; i < 4; i++)
#pragma unroll
    for (int j = 0; j < 4; j++) acc[i][j] = f32x4{0.f, 0.f, 0.f, 0.f};

  for (int k0 = 0; k0 < 1024; k0 += 32) {
    __syncthreads();
    float4 fa[2][2]; int4 vb[2];
#pragma unroll
    for (int ii = 0; ii < 2; ii++) {
      const int p16 = (w * 2 + ii) * 64 + lane;  // 0..511
      const int row = p16 >> 2, cp = p16 & 3;
      const int c = cp ^ ((row >> 1) & 3);
      fa[ii][0] = *(const float4*)(A + (size_t)(m0 + row) * 1024 + k0 + c * 8);
      fa[ii][1] = *(const float4*)(A + (size_t)(m0 + row) * 1024 + k0 + c * 8 + 4);
      vb[ii] = *(const int4*)(Bt + (size_t)(n0 + row) * 1024 + k0 + c * 8);
    }
#pragma unroll
    for (int ii = 0; ii < 2; ii++) {
      const int p16 = (w * 2 + ii) * 64 + lane;
      uint16_t tmp[8];
      tmp[0] = f2bf(fa[ii][0].x); tmp[1] = f2bf(fa[ii][0].y);
      tmp[2] = f2bf(fa[ii][0].z); tmp[3] = f2bf(fa[ii][0].w);
      tmp[4] = f2bf(fa[ii][1].x); tmp[5] = f2bf(fa[ii][1].y);
      tmp[6] = f2bf(fa[ii][1].z); tmp[7] = f2bf(fa[ii][1].w);
      *(int4*)((char*)lA + (size_t)p16 * 16) = *(const int4*)tmp;
      *(int4*)((char*)lB + (size_t)p16 * 16) = vb[ii];
    }
    __syncthreads();
    bf16x8 af[4], bfr[4];
#pragma unroll
    for (int t = 0; t < 4; t++) {
      const int mr = (w >> 1) * 64 + t * 16 + c16;
      af[t] = *(const bf16x8*)((const char*)lA + mr * 64 + ((quad ^ ((mr >> 1) & 3)) * 16));
      const int nr = (w & 1) * 64 + t * 16 + c16;
      bfr[t] = *(const bf16x8*)((const char*)lB + nr * 64 + ((quad ^ ((nr >> 1) & 3)) * 16));
    }
#pragma unroll
    for (int i = 0; i < 4; i++)
#pragma unroll
      for (int j = 0; j < 4; j++) acc[i][j] = mfma16(af[i], bfr[j], acc[i][j]);
  }

  // epilogue. C/D layout per 16x16 tile: col = lane&15, row = quad*4+r.
  const int mbase = m0 + (w >> 1) * 64;
  const int nbase = n0 + (w & 1) * 64;
  float bv[4];
#pragma unroll
  for (int j = 0; j < 4; j++) bv[j] = bias[nbase + j * 16 + c16];
#pragma unroll
  for (int i = 0; i < 4; i++) {
#pragma unroll
    for (int j = 0; j < 4; j++) {
      const int n = nbase + j * 16 + c16;
#pragma unroll
      for (int r = 0; r < 4; r++) {
        const int m = mbase + i * 16 + quad * 4 + r;
        float fv = acc[i][j][r] + bv[j];
        if (EPI == 0) {
          const int region = n >> 10;  // 0=Q 1=K 2=V (uniform per block)
          const int cr = n & 1023;
          const int h = cr >> 6, d = cr & 63;
          if (region == 0)      outQ[((size_t)(h << 12) + m) * 64 + d] = f2bf(fv * 0.125f);
          else if (region == 1) outK[((size_t)(h << 12) + m) * 64 + d] = f2bf(fv);
          else                  outV[((size_t)(h * 64 + d) << 12) + m] = f2bf(fv);  // V^T
        } else {
          outF[(size_t)m * 1024 + n] = fv;
        }
      }
    }
  }
}

// ---------------------------------------------------------------------------
// Flash attention. ONE WAVE per block; wave owns 32 q rows of one head.
// Grid 2048 1-D, bid = qstrip*16 + h  (=> XCD = bid%8 = h%8: each head's KV
// pinned to one XCD's L2). Heavy strips first. S^T = K.Q^T, O^T = Vt.P^T.
// K frags batched before S^T; V frags batched before softmax (latency hides
// under the exp chain). lP per-wave; no barriers anywhere.
// ---------------------------------------------------------------------------
__global__ __launch_bounds__(64) void attn_kernel(const uint16_t* __restrict__ Qb,
                                                  const uint16_t* __restrict__ Kb,
                                                  const uint16_t* __restrict__ Vtb,
                                                  float* __restrict__ Ob) {
  __shared__ __align__(16) uint16_t lP[32 * 128];  // this wave's [q][key], 8KB
  const int lane = threadIdx.x;
  const int quad = lane >> 4, c16 = lane & 15;
  const int bid = blockIdx.x;
  const int h = bid & 15;
  const int qw = 127 - (bid >> 4);   // heavy strips dispatched first
  const int q0w = qw * 32;
  const int jmax = (q0w + 31) >> 7;  // last key tile (causal)

  // Q fragments (B-operand): lane holds q(n)=c16, k(d) = kc*32 + quad*8 + j
  bf16x8 qf[2][2];
#pragma unroll
  for (int nt = 0; nt < 2; nt++)
#pragma unroll
    for (int kc = 0; kc < 2; kc++) {
      int4 v = *(const int4*)(Qb + ((size_t)(h << 12) + q0w + nt * 16 + c16) * 64 + kc * 32 + quad * 8);
      qf[nt][kc] = __builtin_bit_cast(bf16x8, v);
    }

  float ms[2] = {-3.0e38f, -3.0e38f};
  float ls[2] = {0.f, 0.f};
  f32x4 o[4][2];
#pragma unroll
  for (int i = 0; i < 4; i++) { o[i][0] = f32x4{0.f,0.f,0.f,0.f}; o[i][1] = f32x4{0.f,0.f,0.f,0.f}; }

  for (int j = 0; j <= jmax; j++) {
    // ---- batched K fragment loads (16 int4, all in flight before use)
    const uint16_t* kbase = Kb + ((size_t)(h << 12) + j * 128) * 64;
    int4 kf[2][8];
#pragma unroll
    for (int kc = 0; kc < 2; kc++)
#pragma unroll
      for (int mt = 0; mt < 8; mt++)
        kf[kc][mt] = *(const int4*)(kbase + (mt * 16 + c16) * 64 + kc * 32 + quad * 8);

    // ---- S^T = K . Q^T : D[key][q], 8 key-tiles x 2 q-tiles
    f32x4 st[8][2];
#pragma unroll
    for (int mt = 0; mt < 8; mt++) { st[mt][0] = f32x4{0.f,0.f,0.f,0.f}; st[mt][1] = f32x4{0.f,0.f,0.f,0.f}; }
#pragma unroll
    for (int kc = 0; kc < 2; kc++)
#pragma unroll
      for (int mt = 0; mt < 8; mt++) {
        bf16x8 a = __builtin_bit_cast(bf16x8, kf[kc][mt]);
        st[mt][0] = mfma16(a, qf[0][kc], st[mt][0]);
        st[mt][1] = mfma16(a, qf[1][kc], st[mt][1]);
      }

    // ---- batched V fragment loads (independent of softmax: latency hides)
    int4 vf[4][4];
#pragma unroll
    for (int kc = 0; kc < 4; kc++)
#pragma unroll
      for (int mt = 0; mt < 4; mt++)
        vf[kc][mt] = *(const int4*)(Vtb + ((size_t)(h * 64 + mt * 16 + c16) << 12) +
                                    j * 128 + (kc * 4 + quad) * 8);

    // ---- causal mask: only on the diagonal tile (uniform branch)
    if (j == jmax) {
#pragma unroll
      for (int nt = 0; nt < 2; nt++) {
        const int qg = q0w + nt * 16 + c16;
#pragma unroll
        for (int mt = 0; mt < 8; mt++)
#pragma unroll
          for (int r = 0; r < 4; r++) {
            const int key = j * 128 + mt * 16 + quad * 4 + r;
            if (key > qg) st[mt][nt][r] = -1.0e9f;
          }
      }
    }

    // ---- online softmax (per q = c16, state replicated across quads)
#pragma unroll
    for (int nt = 0; nt < 2; nt++) {
      float mx = -3.0e38f;
#pragma unroll
      for (int mt = 0; mt < 8; mt++)
#pragma unroll
        for (int r = 0; r < 4; r++) mx = fmaxf(mx, st[mt][nt][r]);
      mx = fmaxf(mx, __shfl_xor(mx, 16));
      mx = fmaxf(mx, __shfl_xor(mx, 32));
      const float mnew = fmaxf(ms[nt], mx);
      const float alpha = __expf(ms[nt] - mnew);
      float sum = 0.f;
      const int prow = nt * 16 + c16;
      const size_t pbase = (size_t)prow * 256;
#pragma unroll
      for (int mt = 0; mt < 8; mt++) {
        float p0 = __expf(st[mt][nt][0] - mnew);
        float p1 = __expf(st[mt][nt][1] - mnew);
        float p2 = __expf(st[mt][nt][2] - mnew);
        float p3 = __expf(st[mt][nt][3] - mnew);
        sum += p0 + p1 + p2 + p3;
        const unsigned int lo = (unsigned int)f2bf(p0) | ((unsigned int)f2bf(p1) << 16);
        const unsigned int hi = (unsigned int)f2bf(p2) | ((unsigned int)f2bf(p3) << 16);
        const int chunk = mt * 2 + (quad >> 1);
        uint2* dst = (uint2*)((char*)lP + pbase + ((chunk ^ (prow & 15)) << 4) + (quad & 1) * 8);
        *dst = make_uint2(lo, hi);
      }
      sum += __shfl_xor(sum, 16);
      sum += __shfl_xor(sum, 32);
      ls[nt] = alpha * ls[nt] + sum;
      ms[nt] = mnew;
#pragma unroll
      for (int mt = 0; mt < 4; mt++) o[mt][nt] *= alpha;
    }
    // lP is same-wave write->read (in order): no barrier.

    // ---- O^T += Vt . P^T : D[d][q], using prefetched vf
#pragma unroll
    for (int kc = 0; kc < 4; kc++) {
      bf16x8 pb[2];
#pragma unroll
      for (int nt = 0; nt < 2; nt++) {
        const int prow = nt * 16 + c16;
        const int chunk = kc * 4 + quad;
        pb[nt] = *(const bf16x8*)((const char*)lP + (size_t)prow * 256 +
                                  ((chunk ^ (prow & 15)) << 4));
      }
#pragma unroll
      for (int mt = 0; mt < 4; mt++) {
        bf16x8 a = __builtin_bit_cast(bf16x8, vf[kc][mt]);
        o[mt][0] = mfma16(a, pb[0], o[mt][0]);
        o[mt][1] = mfma16(a, pb[1], o[mt][1]);
      }
    }
  }

  // ---- epilogue: Ob[s][h*64+d] = O^T[d][s] / l   (fp32, float4 stores)
#pragma unroll
  for (int nt = 0; nt < 2; nt++) {
    const float inv = 1.f / ls[nt];
    const int qg = q0w + nt * 16 + c16;
#pragma unroll
    for (int mt = 0; mt < 4; mt++) {
      f32x4 v = o[mt][nt] * inv;
      *(f32x4*)(Ob + (size_t)qg * 1024 + h * 64 + mt * 16 + quad * 4) = v;
    }
  }
}

// ---------------------------------------------------------------------------
extern "C" void kernel_launch(void* const* d_in, const int* in_sizes, int n_in,
                              void* d_out, int out_size, void* d_ws, size_t ws_size,
                              hipStream_t stream) {
  const float* x      = (const float*)d_in[0];   // fp32 [1][4096][1024]
  // d_in[1] = attention_mask (fp32): analytically causal, never read
  const float* W_attn = (const float*)d_in[2];   // fp32 [1024][3072]
  const float* b_attn = (const float*)d_in[3];   // fp32 [3072]
  const float* W_proj = (const float*)d_in[4];   // fp32 [1024][1024]
  const float* b_proj = (const float*)d_in[5];   // fp32 [1024]
  float* out = (float*)d_out;                    // fp32 [4096][1024]

  // Workspace (48 MB).
  char* ws = (char*)d_ws;
  float*    Ob  = (float*)(ws);                       // [0,16MB): attn out fp32 [4096][1024]
  uint16_t* wtA = (uint16_t*)(ws + 16777216);         // [16,22MB): W_attn^T bf16 [3072][1024]
  uint16_t* wtP = (uint16_t*)(ws + 23068672);         // [22,24MB): W_proj^T bf16 [1024][1024]
  uint16_t* Qb  = (uint16_t*)(ws + 25165824);         // Q bf16 [16][4096][64] (prescaled 1/8)
  uint16_t* Kb  = (uint16_t*)(ws + 33554432);         // K bf16 [16][4096][64]
  uint16_t* Vtb = (uint16_t*)(ws + 41943040);         // V^T bf16 [16][64][4096]

  transpose_f2b<<<dim3(48, 16), 256, 0, stream>>>(W_attn, wtA, 1024, 3072);
  transpose_f2b<<<dim3(16, 16), 256, 0, stream>>>(W_proj, wtP, 1024, 1024);
  gemm_bt<0><<<dim3(24, 32), 256, 0, stream>>>(x, wtA, b_attn, Qb, Kb, Vtb, nullptr);
  attn_kernel<<<dim3(2048), 64, 0, stream>>>(Qb, Kb, Vtb, Ob);
  gemm_bt<1><<<dim3(8, 32), 256, 0, stream>>>(Ob, wtP, b_proj, nullptr, nullptr, nullptr, out);
}

// Round 8
// 343.474 us; speedup vs baseline: 1.6802x; 1.0522x over previous
//
#include <hip/hip_runtime.h>
#include <stdint.h>

// ---------------------------------------------------------------------------
// GPT2 attention forward, fp32 in/out, bf16 MFMA internally.
// Round 8: (1) attn __launch_bounds__(64,2) -> 256 VGPR budget so the 32
// K/V fragment loads per iteration actually batch (round 7 compiled at 156
// VGPR for a phantom 3rd wave slot and serialized the loads ~300cy each);
// (2) GEMM A-path back to bf16 (x converted once; attn writes Ob bf16).
// ---------------------------------------------------------------------------

typedef __bf16 bf16x8 __attribute__((ext_vector_type(8)));
typedef float f32x4 __attribute__((ext_vector_type(4)));

__device__ __forceinline__ f32x4 mfma16(bf16x8 a, bf16x8 b, f32x4 c) {
  return __builtin_amdgcn_mfma_f32_16x16x32_bf16(a, b, c, 0, 0, 0);
}

__device__ __forceinline__ uint16_t f2bf(float f) {
  unsigned int u = __builtin_bit_cast(unsigned int, f);
  u += 0x7fffu + ((u >> 16) & 1u);
  return (uint16_t)(u >> 16);
}

// ---------------------------------------------------------------------------
// fp32 -> bf16 elementwise, 8 elements/thread.
// ---------------------------------------------------------------------------
__global__ __launch_bounds__(256) void f2b_k(const float* __restrict__ in,
                                             uint16_t* __restrict__ out, int n) {
  const int base = (blockIdx.x * 256 + threadIdx.x) * 8;
  if (base >= n) return;
  float4 a = *(const float4*)(in + base);
  float4 b = *(const float4*)(in + base + 4);
  uint16_t t[8];
  t[0] = f2bf(a.x); t[1] = f2bf(a.y); t[2] = f2bf(a.z); t[3] = f2bf(a.w);
  t[4] = f2bf(b.x); t[5] = f2bf(b.y); t[6] = f2bf(b.z); t[7] = f2bf(b.w);
  *(int4*)(out + base) = *(const int4*)t;
}

// ---------------------------------------------------------------------------
// fused convert+transpose: out_bf16[c][r] = in_f32[r][c]. grid (C/64, R/64).
// ---------------------------------------------------------------------------
__global__ __launch_bounds__(256) void transpose_f2b(const float* __restrict__ in,
                                                     uint16_t* __restrict__ out,
                                                     int R, int C) {
  __shared__ float t[64][65];
  const int tx = threadIdx.x & 15;
  const int ty = threadIdx.x >> 4;
  const int r0 = blockIdx.y * 64, c0 = blockIdx.x * 64;
#pragma unroll
  for (int rr = ty; rr < 64; rr += 16) {
    float4 v = *(const float4*)(in + (size_t)(r0 + rr) * C + c0 + tx * 4);
    t[rr][tx * 4 + 0] = v.x; t[rr][tx * 4 + 1] = v.y;
    t[rr][tx * 4 + 2] = v.z; t[rr][tx * 4 + 3] = v.w;
  }
  __syncthreads();
#pragma unroll
  for (int cc = ty; cc < 64; cc += 16) {
    uint16_t tmp[4];
#pragma unroll
    for (int j = 0; j < 4; j++) tmp[j] = f2bf(t[tx * 4 + j][cc]);
    *(uint2*)(out + (size_t)(c0 + cc) * R + r0 + tx * 4) = *(const uint2*)tmp;
  }
}

// ---------------------------------------------------------------------------
// bt-form GEMM: C[m][n] = A[m][:].Bt[n][:] + bias[n]. A,Bt bf16; bias fp32.
// K=1024, tile 128x128, register round-trip staging.
// EPI==0: QKV scatter (Q prescaled 0.125; outV = V^T [h][d][s]) -> bf16
// EPI==1: plain fp32 epilogue (outF[m*1024+n])
// ---------------------------------------------------------------------------
template <int EPI>
__global__ __launch_bounds__(256) void gemm_bt(const uint16_t* __restrict__ A,
                                               const uint16_t* __restrict__ Bt,
                                               const float* __restrict__ bias,
                                               uint16_t* __restrict__ outQ,
                                               uint16_t* __restrict__ outK,
                                               uint16_t* __restrict__ outV,
                                               float* __restrict__ outF) {
  __shared__ __align__(16) uint16_t lA[128 * 32];
  __shared__ __align__(16) uint16_t lB[128 * 32];
  const int tid = threadIdx.x;
  const int w = tid >> 6, lane = tid & 63;
  const int quad = lane >> 4, c16 = lane & 15;
  const int m0 = blockIdx.y * 128, n0 = blockIdx.x * 128;

  f32x4 acc[4][4];
#pragma unroll
  for (int i = 0; i < 4; i++)
#pragma unroll
    for (int j = 0; j < 4; j++) acc[i][j] = f32x4{0.f, 0.f, 0.f, 0.f};

  // LDS row = 64B = 4 chunks of 16B; chunk swizzle c' = c ^ ((row>>1)&3).
  for (int k0 = 0; k0 < 1024; k0 += 32) {
    __syncthreads();
    int4 va[2], vb[2];
#pragma unroll
    for (int ii = 0; ii < 2; ii++) {
      const int p16 = (w * 2 + ii) * 64 + lane;  // 0..511
      const int row = p16 >> 2, cp = p16 & 3;
      const int c = cp ^ ((row >> 1) & 3);
      va[ii] = *(const int4*)(A + (size_t)(m0 + row) * 1024 + k0 + c * 8);
      vb[ii] = *(const int4*)(Bt + (size_t)(n0 + row) * 1024 + k0 + c * 8);
    }
#pragma unroll
    for (int ii = 0; ii < 2; ii++) {
      const int p16 = (w * 2 + ii) * 64 + lane;
      *(int4*)((char*)lA + (size_t)p16 * 16) = va[ii];
      *(int4*)((char*)lB + (size_t)p16 * 16) = vb[ii];
    }
    __syncthreads();
    bf16x8 af[4], bfr[4];
#pragma unroll
    for (int t = 0; t < 4; t++) {
      const int mr = (w >> 1) * 64 + t * 16 + c16;
      af[t] = *(const bf16x8*)((const char*)lA + mr * 64 + ((quad ^ ((mr >> 1) & 3)) * 16));
      const int nr = (w & 1) * 64 + t * 16 + c16;
      bfr[t] = *(const bf16x8*)((const char*)lB + nr * 64 + ((quad ^ ((nr >> 1) & 3)) * 16));
    }
#pragma unroll
    for (int i = 0; i < 4; i++)
#pragma unroll
      for (int j = 0; j < 4; j++) acc[i][j] = mfma16(af[i], bfr[j], acc[i][j]);
  }

  // epilogue. C/D layout per 16x16 tile: col = lane&15, row = quad*4+r.
  const int mbase = m0 + (w >> 1) * 64;
  const int nbase = n0 + (w & 1) * 64;
  float bv[4];
#pragma unroll
  for (int j = 0; j < 4; j++) bv[j] = bias[nbase + j * 16 + c16];
#pragma unroll
  for (int i = 0; i < 4; i++) {
#pragma unroll
    for (int j = 0; j < 4; j++) {
      const int n = nbase + j * 16 + c16;
#pragma unroll
      for (int r = 0; r < 4; r++) {
        const int m = mbase + i * 16 + quad * 4 + r;
        float fv = acc[i][j][r] + bv[j];
        if (EPI == 0) {
          const int region = n >> 10;  // 0=Q 1=K 2=V (uniform per block)
          const int cr = n & 1023;
          const int h = cr >> 6, d = cr & 63;
          if (region == 0)      outQ[((size_t)(h << 12) + m) * 64 + d] = f2bf(fv * 0.125f);
          else if (region == 1) outK[((size_t)(h << 12) + m) * 64 + d] = f2bf(fv);
          else                  outV[((size_t)(h * 64 + d) << 12) + m] = f2bf(fv);  // V^T
        } else {
          outF[(size_t)m * 1024 + n] = fv;
        }
      }
    }
  }
}

// ---------------------------------------------------------------------------
// Flash attention. ONE WAVE per block; wave owns 32 q rows of one head.
// Grid 2048 1-D, bid = qstrip*16 + h (head pinned to XCD = bid%8).
// __launch_bounds__(64,2): 256-VGPR budget so kf[16]/vf[16] fully batch
// (kf dead before vf peak; phase-peak live set ~210 VGPR).
// ---------------------------------------------------------------------------
__global__ __launch_bounds__(64, 2) void attn_kernel(const uint16_t* __restrict__ Qb,
                                                     const uint16_t* __restrict__ Kb,
                                                     const uint16_t* __restrict__ Vtb,
                                                     uint16_t* __restrict__ Ob) {
  __shared__ __align__(16) uint16_t lP[32 * 128];  // this wave's [q][key], 8KB
  const int lane = threadIdx.x;
  const int quad = lane >> 4, c16 = lane & 15;
  const int bid = blockIdx.x;
  const int h = bid & 15;
  const int qw = 127 - (bid >> 4);   // heavy strips dispatched first
  const int q0w = qw * 32;
  const int jmax = (q0w + 31) >> 7;  // last key tile (causal)

  // Q fragments (B-operand): lane holds q(n)=c16, k(d) = kc*32 + quad*8 + j
  bf16x8 qf[2][2];
#pragma unroll
  for (int nt = 0; nt < 2; nt++)
#pragma unroll
    for (int kc = 0; kc < 2; kc++) {
      int4 v = *(const int4*)(Qb + ((size_t)(h << 12) + q0w + nt * 16 + c16) * 64 + kc * 32 + quad * 8);
      qf[nt][kc] = __builtin_bit_cast(bf16x8, v);
    }

  float ms[2] = {-3.0e38f, -3.0e38f};
  float ls[2] = {0.f, 0.f};
  f32x4 o[4][2];
#pragma unroll
  for (int i = 0; i < 4; i++) { o[i][0] = f32x4{0.f,0.f,0.f,0.f}; o[i][1] = f32x4{0.f,0.f,0.f,0.f}; }

  for (int j = 0; j <= jmax; j++) {
    // ---- batched K fragment loads (16 int4, all in flight before use)
    const uint16_t* kbase = Kb + ((size_t)(h << 12) + j * 128) * 64;
    int4 kf[2][8];
#pragma unroll
    for (int kc = 0; kc < 2; kc++)
#pragma unroll
      for (int mt = 0; mt < 8; mt++)
        kf[kc][mt] = *(const int4*)(kbase + (mt * 16 + c16) * 64 + kc * 32 + quad * 8);

    // ---- S^T = K . Q^T : D[key][q], 8 key-tiles x 2 q-tiles
    f32x4 st[8][2];
#pragma unroll
    for (int mt = 0; mt < 8; mt++) { st[mt][0] = f32x4{0.f,0.f,0.f,0.f}; st[mt][1] = f32x4{0.f,0.f,0.f,0.f}; }
#pragma unroll
    for (int kc = 0; kc < 2; kc++)
#pragma unroll
      for (int mt = 0; mt < 8; mt++) {
        bf16x8 a = __builtin_bit_cast(bf16x8, kf[kc][mt]);
        st[mt][0] = mfma16(a, qf[0][kc], st[mt][0]);
        st[mt][1] = mfma16(a, qf[1][kc], st[mt][1]);
      }

    // ---- batched V fragment loads (independent of softmax: latency hides)
    int4 vf[4][4];
#pragma unroll
    for (int kc = 0; kc < 4; kc++)
#pragma unroll
      for (int mt = 0; mt < 4; mt++)
        vf[kc][mt] = *(const int4*)(Vtb + ((size_t)(h * 64 + mt * 16 + c16) << 12) +
                                    j * 128 + (kc * 4 + quad) * 8);

    // ---- causal mask: only on the diagonal tile (uniform branch)
    if (j == jmax) {
#pragma unroll
      for (int nt = 0; nt < 2; nt++) {
        const int qg = q0w + nt * 16 + c16;
#pragma unroll
        for (int mt = 0; mt < 8; mt++)
#pragma unroll
          for (int r = 0; r < 4; r++) {
            const int key = j * 128 + mt * 16 + quad * 4 + r;
            if (key > qg) st[mt][nt][r] = -1.0e9f;
          }
      }
    }

    // ---- online softmax (per q = c16, state replicated across quads)
#pragma unroll
    for (int nt = 0; nt < 2; nt++) {
      float mx = -3.0e38f;
#pragma unroll
      for (int mt = 0; mt < 8; mt++)
#pragma unroll
        for (int r = 0; r < 4; r++) mx = fmaxf(mx, st[mt][nt][r]);
      mx = fmaxf(mx, __shfl_xor(mx, 16));
      mx = fmaxf(mx, __shfl_xor(mx, 32));
      const float mnew = fmaxf(ms[nt], mx);
      const float alpha = __expf(ms[nt] - mnew);
      float sum = 0.f;
      const int prow = nt * 16 + c16;
      const size_t pbase = (size_t)prow * 256;
#pragma unroll
      for (int mt = 0; mt < 8; mt++) {
        float p0 = __expf(st[mt][nt][0] - mnew);
        float p1 = __expf(st[mt][nt][1] - mnew);
        float p2 = __expf(st[mt][nt][2] - mnew);
        float p3 = __expf(st[mt][nt][3] - mnew);
        sum += p0 + p1 + p2 + p3;
        const unsigned int lo = (unsigned int)f2bf(p0) | ((unsigned int)f2bf(p1) << 16);
        const unsigned int hi = (unsigned int)f2bf(p2) | ((unsigned int)f2bf(p3) << 16);
        const int chunk = mt * 2 + (quad >> 1);
        uint2* dst = (uint2*)((char*)lP + pbase + ((chunk ^ (prow & 15)) << 4) + (quad & 1) * 8);
        *dst = make_uint2(lo, hi);
      }
      sum += __shfl_xor(sum, 16);
      sum += __shfl_xor(sum, 32);
      ls[nt] = alpha * ls[nt] + sum;
      ms[nt] = mnew;
#pragma unroll
      for (int mt = 0; mt < 4; mt++) o[mt][nt] *= alpha;
    }
    // lP is same-wave write->read (in order): no barrier.

    // ---- O^T += Vt . P^T : D[d][q], using prefetched vf
#pragma unroll
    for (int kc = 0; kc < 4; kc++) {
      bf16x8 pb[2];
#pragma unroll
      for (int nt = 0; nt < 2; nt++) {
        const int prow = nt * 16 + c16;
        const int chunk = kc * 4 + quad;
        pb[nt] = *(const bf16x8*)((const char*)lP + (size_t)prow * 256 +
                                  ((chunk ^ (prow & 15)) << 4));
      }
#pragma unroll
      for (int mt = 0; mt < 4; mt++) {
        bf16x8 a = __builtin_bit_cast(bf16x8, vf[kc][mt]);
        o[mt][0] = mfma16(a, pb[0], o[mt][0]);
        o[mt][1] = mfma16(a, pb[1], o[mt][1]);
      }
    }
  }

  // ---- epilogue: Ob[s][h*64+d] = O^T[d][s] / l   (bf16, 8B stores)
#pragma unroll
  for (int nt = 0; nt < 2; nt++) {
    const float inv = 1.f / ls[nt];
    const int qg = q0w + nt * 16 + c16;
#pragma unroll
    for (int mt = 0; mt < 4; mt++) {
      uint16_t tmp[4];
#pragma unroll
      for (int r = 0; r < 4; r++) tmp[r] = f2bf(o[mt][nt][r] * inv);
      *(uint2*)(Ob + (size_t)qg * 1024 + h * 64 + mt * 16 + quad * 4) = *(const uint2*)tmp;
    }
  }
}

// ---------------------------------------------------------------------------
extern "C" void kernel_launch(void* const* d_in, const int* in_sizes, int n_in,
                              void* d_out, int out_size, void* d_ws, size_t ws_size,
                              hipStream_t stream) {
  const float* x      = (const float*)d_in[0];   // fp32 [1][4096][1024]
  // d_in[1] = attention_mask (fp32): analytically causal, never read
  const float* W_attn = (const float*)d_in[2];   // fp32 [1024][3072]
  const float* b_attn = (const float*)d_in[3];   // fp32 [3072]
  const float* W_proj = (const float*)d_in[4];   // fp32 [1024][1024]
  const float* b_proj = (const float*)d_in[5];   // fp32 [1024]
  float* out = (float*)d_out;                    // fp32 [4096][1024]

  // Workspace (48 MB).
  char* ws = (char*)d_ws;
  uint16_t* Ob  = (uint16_t*)(ws);                    // [0,8MB): attn out bf16 [4096][1024]
  uint16_t* wtA = (uint16_t*)(ws + 8388608);          // [8,14MB): W_attn^T bf16 [3072][1024]
  uint16_t* wtP = (uint16_t*)(ws + 14680064);         // [14,16MB): W_proj^T bf16 [1024][1024]
  uint16_t* Qb  = (uint16_t*)(ws + 16777216);         // [16,24MB): Q bf16 (prescaled 1/8)
  uint16_t* Kb  = (uint16_t*)(ws + 25165824);         // [24,32MB): K bf16
  uint16_t* Vtb = (uint16_t*)(ws + 33554432);         // [32,40MB): V^T bf16
  uint16_t* xb  = (uint16_t*)(ws + 41943040);         // [40,48MB): x bf16 [4096][1024]

  f2b_k<<<2048, 256, 0, stream>>>(x, xb, 4096 * 1024);
  transpose_f2b<<<dim3(48, 16), 256, 0, stream>>>(W_attn, wtA, 1024, 3072);
  transpose_f2b<<<dim3(16, 16), 256, 0, stream>>>(W_proj, wtP, 1024, 1024);
  gemm_bt<0><<<dim3(24, 32), 256, 0, stream>>>(xb, wtA, b_attn, Qb, Kb, Vtb, nullptr);
  attn_kernel<<<dim3(2048), 64, 0, stream>>>(Qb, Kb, Vtb, Ob);
  gemm_bt<1><<<dim3(8, 32), 256, 0, stream>>>(Ob, wtP, b_proj, nullptr, nullptr, nullptr, out);
}